// Round 1
// baseline (422.275 us; speedup 1.0000x reference)
//
#include <hip/hip_runtime.h>
#include <cstdint>
#include <cstddef>

#define NBg 64    // num gt slots
#define NCg 80    // num classes
#define KTOP 10

// CIoU exactly mirroring the reference op order, f32, no FMA contraction.
// atan/pow done in double then rounded -> approximates correctly-rounded f32 libm.
__device__ __forceinline__ float ciou_dev(float gx1, float gy1, float gx2, float gy2,
                                          float px1, float py1, float px2, float py2) {
#pragma clang fp contract(off)
  const float keps = 1e-7f;
  float w1 = gx2 - gx1;
  float h1 = (gy2 - gy1) + keps;
  float w2 = px2 - px1;
  float h2 = (py2 - py1) + keps;
  float iw = fminf(gx2, px2) - fmaxf(gx1, px1);
  float ih = fminf(gy2, py2) - fmaxf(gy1, py1);
  float inter = fmaxf(iw, 0.0f) * fmaxf(ih, 0.0f);
  float uni = w1 * h1 + w2 * h2 - inter + keps;
  float iou = inter / uni;
  float cw = fmaxf(gx2, px2) - fminf(gx1, px1);
  float ch = fmaxf(gy2, py2) - fminf(gy1, py1);
  float c2 = cw * cw + ch * ch + keps;
  float dx = (gx1 + gx2) * 0.5f - (px1 + px2) * 0.5f;
  float dy = (gy1 + gy2) * 0.5f - (py1 + py2) * 0.5f;
  float rho2 = dx * dx + dy * dy;
  float q2 = w2 / h2;           // f32 divide (correctly rounded), then CR atan
  float q1 = w1 / h1;
  float t = (float)atan((double)q2) - (float)atan((double)q1);
  float v = 0.4052847345693511f * (t * t);   // 4/pi^2 cast to f32 like numpy scalar cast
  float alpha = v / ((v - iou) + 1.0000001f); // (1.0 + 1e-7) rounded to f32
  return iou - (rho2 / c2 + v * alpha);
}

// K1: align_metric[b][j][a] for valid j (mask_gt true). Rows for invalid j untouched.
__global__ void k1_align(const float* __restrict__ pd_scores,
                         const float* __restrict__ pd_bboxes,
                         const float* __restrict__ anc,
                         const float* __restrict__ gt_labels,
                         const float* __restrict__ gt_bboxes,
                         const int* __restrict__ mask_gt,
                         float* __restrict__ align,
                         int NA) {
  int b = blockIdx.y;
  int a = blockIdx.x * blockDim.x + threadIdx.x;
  __shared__ float4 sg[NBg];
  __shared__ int slbl[NBg];
  __shared__ int svalid[NBg];
  __shared__ int sglpos[NBg];
  if (threadIdx.x < NBg) {
    int j = threadIdx.x;
    const float* g = gt_bboxes + ((size_t)b * NBg + j) * 4;
    sg[j] = make_float4(g[0], g[1], g[2], g[3]);
    float gl = gt_labels[b * NBg + j];
    slbl[j] = gl > 0.0f ? (int)gl : 0;
    sglpos[j] = (gl >= 0.0f) ? 1 : 0;
    svalid[j] = mask_gt[b * NBg + j];
  }
  __syncthreads();
  if (a >= NA) return;
  float ax = anc[2 * a], ay = anc[2 * a + 1];
  const float* pb = pd_bboxes + ((size_t)b * NA + a) * 4;
  float px1 = pb[0], py1 = pb[1], px2 = pb[2], py2 = pb[3];
  const float* ps = pd_scores + ((size_t)b * NA + a) * NCg;
  for (int j = 0; j < NBg; j++) {
    if (!svalid[j]) continue;
    float4 g = sg[j];
    float dmin = fminf(fminf(ax - g.x, ay - g.y), fminf(g.z - ax, g.w - ay));
    float am = 0.0f;
    if (dmin > 1e-9f) {
      float ci = ciou_dev(g.x, g.y, g.z, g.w, px1, py1, px2, py2);
      float ov = ci > 0.0f ? ci : 0.0f;
      float sc = sglpos[j] ? ps[slbl[j]] : 0.0f;
      // power(sc, 0.5) * power(ov, 6.0), near-correctly-rounded f32
      am = (float)pow((double)sc, 0.5) * (float)pow((double)ov, 6.0);
    }
    align[((size_t)(b * NBg + j)) * NA + a] = am;
  }
}

// K2: exact top-10 per (b,j) row, jax tie semantics (value desc, index asc).
// 10 passes of block-wide argmax with exclusion of already-selected indices.
// Scatter mask into transposed maskT[b][a][j] (byte), only if anchor in gt box.
__global__ void k2_topk(const float* __restrict__ align,
                        const float* __restrict__ anc,
                        const float* __restrict__ gt_bboxes,
                        const int* __restrict__ mask_gt,
                        unsigned char* __restrict__ maskT,
                        int NA) {
  int j = blockIdx.x;
  int b = blockIdx.y;
  if (!mask_gt[b * NBg + j]) return;  // invalid gt contributes nothing
  const float* row = align + ((size_t)(b * NBg + j)) * NA;
  __shared__ float sv[256];
  __shared__ int si[256];
  __shared__ int ssel[KTOP];
  int tid = threadIdx.x;
  for (int p = 0; p < KTOP; p++) {
    float bv = -1.0f;
    int bi = NA;
    for (int a = tid; a < NA; a += 256) {
      bool used = false;
      for (int q = 0; q < p; q++) used |= (ssel[q] == a);
      if (used) continue;
      float vv = row[a];
      if (vv > bv) { bv = vv; bi = a; }  // strict > keeps smallest index on ties
    }
    sv[tid] = bv; si[tid] = bi;
    __syncthreads();
    for (int s = 128; s > 0; s >>= 1) {
      if (tid < s) {
        float v2 = sv[tid + s]; int i2 = si[tid + s];
        if (v2 > sv[tid] || (v2 == sv[tid] && i2 < si[tid])) { sv[tid] = v2; si[tid] = i2; }
      }
      __syncthreads();
    }
    if (tid == 0) ssel[p] = si[0];
    __syncthreads();
  }
  if (tid < KTOP) {
    int a = ssel[tid];
    float ax = anc[2 * a], ay = anc[2 * a + 1];
    const float* g = gt_bboxes + ((size_t)b * NBg + j) * 4;
    float dmin = fminf(fminf(ax - g[0], ay - g[1]), fminf(g[2] - ax, g[3] - ay));
    if (dmin > 1e-9f) maskT[((size_t)b * NA + a) * NBg + j] = 1;
  }
}

// K3: per (b,a) resolve multi-matches, write target_bboxes + fg, target idx,
// and atomic-max pos_align / pos_overlaps per gt.
__global__ void k3_resolve(const float* __restrict__ pd_bboxes,
                           const float* __restrict__ anc,
                           const float* __restrict__ gt_bboxes,
                           const int* __restrict__ mask_gt,
                           const unsigned char* __restrict__ maskT,
                           const float* __restrict__ align,
                           int* __restrict__ tgt,
                           float* __restrict__ out_tb,
                           float* __restrict__ out_fg,
                           float* __restrict__ posAlign,
                           float* __restrict__ posOv,
                           int NA) {
  int b = blockIdx.y;
  int a = blockIdx.x * blockDim.x + threadIdx.x;
  __shared__ float4 sg[NBg];
  __shared__ int svalid[NBg];
  if (threadIdx.x < NBg) {
    int j = threadIdx.x;
    const float* g = gt_bboxes + ((size_t)b * NBg + j) * 4;
    sg[j] = make_float4(g[0], g[1], g[2], g[3]);
    svalid[j] = mask_gt[b * NBg + j];
  }
  __syncthreads();
  if (a >= NA) return;
  const unsigned int* mu = (const unsigned int*)(maskT + ((size_t)b * NA + a) * NBg);
  int cnt = 0, first = 0;
  bool any = false;
  for (int w = 0; w < 16; w++) {
    unsigned int x = mu[w];
    if (x) {
      cnt += __popc(x);  // bytes are 0/1 -> popcount == byte count
      if (!any) { first = w * 4 + ((__ffs(x) - 1) >> 3); any = true; }
    }
  }
  float ax = anc[2 * a], ay = anc[2 * a + 1];
  const float* pb = pd_bboxes + ((size_t)b * NA + a) * 4;
  float px1 = pb[0], py1 = pb[1], px2 = pb[2], py2 = pb[3];
  int t = 0;
  float fg = 0.0f;
  float ovt = -1.0f;
  if (cnt == 1) {
    t = first; fg = 1.0f;
  } else if (cnt > 1) {
    // argmax_j overlaps[b,j,a], first occurrence of max (jnp.argmax semantics)
    float best = -1.0f;
    for (int jj = 0; jj < NBg; jj++) {
      float ov = 0.0f;
      if (svalid[jj]) {
        float4 g = sg[jj];
        float dmin = fminf(fminf(ax - g.x, ay - g.y), fminf(g.z - ax, g.w - ay));
        if (dmin > 1e-9f) {
          float ci = ciou_dev(g.x, g.y, g.z, g.w, px1, py1, px2, py2);
          ov = ci > 0.0f ? ci : 0.0f;
        }
      }
      if (ov > best) { best = ov; t = jj; }
    }
    fg = 1.0f;
    ovt = best;
  }
  tgt[(size_t)b * NA + a] = t;
  out_fg[(size_t)b * NA + a] = fg;
  float4 gb = sg[t];
  ((float4*)out_tb)[(size_t)b * NA + a] = gb;
  if (fg > 0.0f) {
    float av = align[((size_t)(b * NBg + t)) * NA + a];
    atomicMax((int*)(posAlign + b * NBg + t), __float_as_int(av));
    float ov;
    if (ovt >= 0.0f) {
      ov = ovt;
    } else {
      float4 g = sg[t];
      float ci = ciou_dev(g.x, g.y, g.z, g.w, px1, py1, px2, py2);
      ov = ci > 0.0f ? ci : 0.0f;  // t came from mask -> in-box & valid
    }
    atomicMax((int*)(posOv + b * NBg + t), __float_as_int(ov));
  }
}

// K5: norm + one-hot target_scores.
__global__ void k5_scores(const float* __restrict__ gt_labels,
                          const int* __restrict__ tgt,
                          const float* __restrict__ out_fg,
                          const float* __restrict__ align,
                          const float* __restrict__ posAlign,
                          const float* __restrict__ posOv,
                          float* __restrict__ out_ts,
                          int NA) {
  int b = blockIdx.y;
  int a = blockIdx.x * blockDim.x + threadIdx.x;
  if (a >= NA) return;
  int t = tgt[(size_t)b * NA + a];
  float fg = out_fg[(size_t)b * NA + a];
  float norm = 0.0f;
  int lbl = -1;
  if (fg > 0.0f) {
    float av = align[((size_t)(b * NBg + t)) * NA + a];
    norm = av * posOv[b * NBg + t] / (posAlign[b * NBg + t] + 1e-9f);
    float gl = gt_labels[b * NBg + t];
    lbl = gl > 0.0f ? (int)gl : 0;
  }
  float4* o = (float4*)(out_ts + ((size_t)b * NA + a) * NCg);
#pragma unroll
  for (int c = 0; c < NCg; c += 4) {
    float4 w = make_float4(0.0f, 0.0f, 0.0f, 0.0f);
    int d = lbl - c;
    if (d >= 0 && d < 4) ((float*)&w)[d] = norm;
    o[c >> 2] = w;
  }
}

extern "C" void kernel_launch(void* const* d_in, const int* in_sizes, int n_in,
                              void* d_out, int out_size, void* d_ws, size_t ws_size,
                              hipStream_t stream) {
  const float* pd_scores = (const float*)d_in[0];
  const float* pd_bboxes = (const float*)d_in[1];
  const float* anc       = (const float*)d_in[2];
  const float* gt_labels = (const float*)d_in[3];
  const float* gt_bboxes = (const float*)d_in[4];
  const int*   mask_gt   = (const int*)d_in[5];

  int NA = in_sizes[2] / 2;       // 8400
  int B  = in_sizes[3] / NBg;     // 16
  size_t nBA = (size_t)B * NA;

  float* out_tb = (float*)d_out;              // (B,NA,4)
  float* out_ts = out_tb + nBA * 4;           // (B,NA,80)
  float* out_fg = out_ts + nBA * NCg;         // (B,NA)

  char* ws = (char*)d_ws;
  size_t off = 0;
  float* align = (float*)(ws + off);          off += nBA * NBg * 4;   // 34.4 MB
  unsigned char* maskT = (unsigned char*)(ws + off); off += nBA * NBg; // 8.6 MB
  int* tgt = (int*)(ws + off);                off += nBA * 4;
  float* posAlign = (float*)(ws + off);       off += (size_t)B * NBg * 4;
  float* posOv = (float*)(ws + off);          off += (size_t)B * NBg * 4;

  hipMemsetAsync(maskT, 0, nBA * NBg, stream);
  hipMemsetAsync(posAlign, 0, (size_t)B * NBg * 4 * 2, stream);  // posAlign+posOv contiguous

  dim3 blk(256);
  dim3 gA((NA + 255) / 256, B);
  k1_align<<<gA, blk, 0, stream>>>(pd_scores, pd_bboxes, anc, gt_labels, gt_bboxes,
                                   mask_gt, align, NA);
  dim3 gT(NBg, B);
  k2_topk<<<gT, blk, 0, stream>>>(align, anc, gt_bboxes, mask_gt, maskT, NA);
  k3_resolve<<<gA, blk, 0, stream>>>(pd_bboxes, anc, gt_bboxes, mask_gt, maskT, align,
                                     tgt, out_tb, out_fg, posAlign, posOv, NA);
  k5_scores<<<gA, blk, 0, stream>>>(gt_labels, tgt, out_fg, align, posAlign, posOv,
                                    out_ts, NA);
}

// Round 2
// 281.299 us; speedup vs baseline: 1.5012x; 1.5012x over previous
//
#include <hip/hip_runtime.h>
#include <cstdint>
#include <cstddef>

#define NBg 64    // num gt slots
#define NCg 80    // num classes
#define KTOP 10

// CIoU exactly mirroring the reference op order, f32, no FMA contraction.
// atan done in double then rounded -> approximates correctly-rounded f32 libm.
__device__ __forceinline__ float ciou_dev(float gx1, float gy1, float gx2, float gy2,
                                          float px1, float py1, float px2, float py2) {
#pragma clang fp contract(off)
  const float keps = 1e-7f;
  float w1 = gx2 - gx1;
  float h1 = (gy2 - gy1) + keps;
  float w2 = px2 - px1;
  float h2 = (py2 - py1) + keps;
  float iw = fminf(gx2, px2) - fmaxf(gx1, px1);
  float ih = fminf(gy2, py2) - fmaxf(gy1, py1);
  float inter = fmaxf(iw, 0.0f) * fmaxf(ih, 0.0f);
  float uni = w1 * h1 + w2 * h2 - inter + keps;
  float iou = inter / uni;
  float cw = fmaxf(gx2, px2) - fminf(gx1, px1);
  float ch = fmaxf(gy2, py2) - fminf(gy1, py1);
  float c2 = cw * cw + ch * ch + keps;
  float dx = (gx1 + gx2) * 0.5f - (px1 + px2) * 0.5f;
  float dy = (gy1 + gy2) * 0.5f - (py1 + py2) * 0.5f;
  float rho2 = dx * dx + dy * dy;
  float q2 = w2 / h2;
  float q1 = w1 / h1;
  float t = (float)atan((double)q2) - (float)atan((double)q1);
  float v = 0.4052847345693511f * (t * t);
  float alpha = v / ((v - iou) + 1.0000001f);
  return iou - (rho2 / c2 + v * alpha);
}

// K1: align_metric[b][j][a] for valid j (mask_gt true). Rows for invalid j untouched.
__global__ void k1_align(const float* __restrict__ pd_scores,
                         const float* __restrict__ pd_bboxes,
                         const float* __restrict__ anc,
                         const float* __restrict__ gt_labels,
                         const float* __restrict__ gt_bboxes,
                         const int* __restrict__ mask_gt,
                         float* __restrict__ align,
                         int NA) {
  int b = blockIdx.y;
  int a = blockIdx.x * blockDim.x + threadIdx.x;
  __shared__ float4 sg[NBg];
  __shared__ int slbl[NBg];
  __shared__ int svalid[NBg];
  __shared__ int sglpos[NBg];
  if (threadIdx.x < NBg) {
    int j = threadIdx.x;
    const float* g = gt_bboxes + ((size_t)b * NBg + j) * 4;
    sg[j] = make_float4(g[0], g[1], g[2], g[3]);
    float gl = gt_labels[b * NBg + j];
    slbl[j] = gl > 0.0f ? (int)gl : 0;
    sglpos[j] = (gl >= 0.0f) ? 1 : 0;
    svalid[j] = mask_gt[b * NBg + j];
  }
  __syncthreads();
  if (a >= NA) return;
  float ax = anc[2 * a], ay = anc[2 * a + 1];
  const float* pb = pd_bboxes + ((size_t)b * NA + a) * 4;
  float px1 = pb[0], py1 = pb[1], px2 = pb[2], py2 = pb[3];
  const float* ps = pd_scores + ((size_t)b * NA + a) * NCg;
  for (int j = 0; j < NBg; j++) {
    if (!svalid[j]) continue;
    float4 g = sg[j];
    float dmin = fminf(fminf(ax - g.x, ay - g.y), fminf(g.z - ax, g.w - ay));
    float am = 0.0f;
    if (dmin > 1e-9f) {
      float ci = ciou_dev(g.x, g.y, g.z, g.w, px1, py1, px2, py2);
      float ov = ci > 0.0f ? ci : 0.0f;
      float sc = sglpos[j] ? ps[slbl[j]] : 0.0f;
      // power(sc,0.5) == CR sqrt; power(ov,6) via exact-ish double products.
      float f1 = (float)sqrt((double)sc);
      double o = (double)ov;
      double o3 = o * o * o;
      float f2 = (float)(o3 * o3);
      am = f1 * f2;
    }
    align[((size_t)(b * NBg + j)) * NA + a] = am;
  }
}

// K2: exact top-10 per (b,j) row, jax tie semantics (value desc, index asc).
// Single pass: one wave per row; per-lane sorted top-10 in registers, then
// 10 shuffle-butterfly pops to merge. Scatter mask into maskT[b][a][j].
__global__ void k2_topk(const float* __restrict__ align,
                        const float* __restrict__ anc,
                        const float* __restrict__ gt_bboxes,
                        const int* __restrict__ mask_gt,
                        unsigned char* __restrict__ maskT,
                        int NA) {
  int wid = threadIdx.x >> 6;
  int lane = threadIdx.x & 63;
  int row = blockIdx.x * (blockDim.x >> 6) + wid;   // b*64 + j
  int b = row >> 6;
  int j = row & 63;
  if (!mask_gt[b * NBg + j]) return;  // wave-uniform
  const float* r = align + (size_t)row * NA;

  float v[KTOP];
  int id[KTOP];
#pragma unroll
  for (int k = 0; k < KTOP; k++) { v[k] = -1.0f; id[k] = 1 << 30; }

  for (int a = lane; a < NA; a += 64) {
    float val = r[a];
    if (val > v[KTOP - 1] || (val == v[KTOP - 1] && a < id[KTOP - 1])) {
      v[KTOP - 1] = val; id[KTOP - 1] = a;
#pragma unroll
      for (int k = KTOP - 1; k > 0; k--) {
        bool sw = v[k] > v[k - 1] || (v[k] == v[k - 1] && id[k] < id[k - 1]);
        if (sw) {
          float tv = v[k]; v[k] = v[k - 1]; v[k - 1] = tv;
          int ti = id[k]; id[k] = id[k - 1]; id[k - 1] = ti;
        }
      }
    }
  }

  int mysel = 0;
#pragma unroll
  for (int p = 0; p < KTOP; p++) {
    float bv = v[0]; int bi = id[0];
#pragma unroll
    for (int m = 1; m < 64; m <<= 1) {
      float ov_ = __shfl_xor(bv, m, 64);
      int oi = __shfl_xor(bi, m, 64);
      if (ov_ > bv || (ov_ == bv && oi < bi)) { bv = ov_; bi = oi; }
    }
    if (lane == p) mysel = bi;
    if (id[0] == bi) {   // this lane owned the winner: pop it
#pragma unroll
      for (int k = 0; k < KTOP - 1; k++) { v[k] = v[k + 1]; id[k] = id[k + 1]; }
      v[KTOP - 1] = -1.0f; id[KTOP - 1] = 1 << 30;
    }
  }

  if (lane < KTOP) {
    int a = mysel;
    float ax = anc[2 * a], ay = anc[2 * a + 1];
    const float* g = gt_bboxes + ((size_t)b * NBg + j) * 4;
    float dmin = fminf(fminf(ax - g[0], ay - g[1]), fminf(g[2] - ax, g[3] - ay));
    if (dmin > 1e-9f) maskT[((size_t)b * NA + a) * NBg + j] = 1;
  }
}

// K3: per (b,a) resolve multi-matches, write target_bboxes + fg, target idx,
// and atomic-max pos_align / pos_overlaps per gt.
__global__ void k3_resolve(const float* __restrict__ pd_bboxes,
                           const float* __restrict__ anc,
                           const float* __restrict__ gt_bboxes,
                           const int* __restrict__ mask_gt,
                           const unsigned char* __restrict__ maskT,
                           const float* __restrict__ align,
                           int* __restrict__ tgt,
                           float* __restrict__ out_tb,
                           float* __restrict__ out_fg,
                           float* __restrict__ posAlign,
                           float* __restrict__ posOv,
                           int NA) {
  int b = blockIdx.y;
  int a = blockIdx.x * blockDim.x + threadIdx.x;
  __shared__ float4 sg[NBg];
  __shared__ int svalid[NBg];
  if (threadIdx.x < NBg) {
    int j = threadIdx.x;
    const float* g = gt_bboxes + ((size_t)b * NBg + j) * 4;
    sg[j] = make_float4(g[0], g[1], g[2], g[3]);
    svalid[j] = mask_gt[b * NBg + j];
  }
  __syncthreads();
  if (a >= NA) return;
  const unsigned int* mu = (const unsigned int*)(maskT + ((size_t)b * NA + a) * NBg);
  int cnt = 0, first = 0;
  bool any = false;
  for (int w = 0; w < 16; w++) {
    unsigned int x = mu[w];
    if (x) {
      cnt += __popc(x);
      if (!any) { first = w * 4 + ((__ffs(x) - 1) >> 3); any = true; }
    }
  }
  float ax = anc[2 * a], ay = anc[2 * a + 1];
  const float* pb = pd_bboxes + ((size_t)b * NA + a) * 4;
  float px1 = pb[0], py1 = pb[1], px2 = pb[2], py2 = pb[3];
  int t = 0;
  float fg = 0.0f;
  float ovt = -1.0f;
  if (cnt == 1) {
    t = first; fg = 1.0f;
  } else if (cnt > 1) {
    float best = -1.0f;
    for (int jj = 0; jj < NBg; jj++) {
      float ov = 0.0f;
      if (svalid[jj]) {
        float4 g = sg[jj];
        float dmin = fminf(fminf(ax - g.x, ay - g.y), fminf(g.z - ax, g.w - ay));
        if (dmin > 1e-9f) {
          float ci = ciou_dev(g.x, g.y, g.z, g.w, px1, py1, px2, py2);
          ov = ci > 0.0f ? ci : 0.0f;
        }
      }
      if (ov > best) { best = ov; t = jj; }
    }
    fg = 1.0f;
    ovt = best;
  }
  tgt[(size_t)b * NA + a] = t;
  out_fg[(size_t)b * NA + a] = fg;
  float4 gb = sg[t];
  ((float4*)out_tb)[(size_t)b * NA + a] = gb;
  if (fg > 0.0f) {
    float av = align[((size_t)(b * NBg + t)) * NA + a];
    atomicMax((int*)(posAlign + b * NBg + t), __float_as_int(av));
    float ov;
    if (ovt >= 0.0f) {
      ov = ovt;
    } else {
      float4 g = sg[t];
      float ci = ciou_dev(g.x, g.y, g.z, g.w, px1, py1, px2, py2);
      ov = ci > 0.0f ? ci : 0.0f;
    }
    atomicMax((int*)(posOv + b * NBg + t), __float_as_int(ov));
  }
}

// K5: norm + one-hot target_scores.
__global__ void k5_scores(const float* __restrict__ gt_labels,
                          const int* __restrict__ tgt,
                          const float* __restrict__ out_fg,
                          const float* __restrict__ align,
                          const float* __restrict__ posAlign,
                          const float* __restrict__ posOv,
                          float* __restrict__ out_ts,
                          int NA) {
  int b = blockIdx.y;
  int a = blockIdx.x * blockDim.x + threadIdx.x;
  if (a >= NA) return;
  int t = tgt[(size_t)b * NA + a];
  float fg = out_fg[(size_t)b * NA + a];
  float norm = 0.0f;
  int lbl = -1;
  if (fg > 0.0f) {
    float av = align[((size_t)(b * NBg + t)) * NA + a];
    norm = av * posOv[b * NBg + t] / (posAlign[b * NBg + t] + 1e-9f);
    float gl = gt_labels[b * NBg + t];
    lbl = gl > 0.0f ? (int)gl : 0;
  }
  float4* o = (float4*)(out_ts + ((size_t)b * NA + a) * NCg);
#pragma unroll
  for (int c = 0; c < NCg; c += 4) {
    float4 w = make_float4(0.0f, 0.0f, 0.0f, 0.0f);
    int d = lbl - c;
    if (d >= 0 && d < 4) ((float*)&w)[d] = norm;
    o[c >> 2] = w;
  }
}

extern "C" void kernel_launch(void* const* d_in, const int* in_sizes, int n_in,
                              void* d_out, int out_size, void* d_ws, size_t ws_size,
                              hipStream_t stream) {
  const float* pd_scores = (const float*)d_in[0];
  const float* pd_bboxes = (const float*)d_in[1];
  const float* anc       = (const float*)d_in[2];
  const float* gt_labels = (const float*)d_in[3];
  const float* gt_bboxes = (const float*)d_in[4];
  const int*   mask_gt   = (const int*)d_in[5];

  int NA = in_sizes[2] / 2;       // 8400
  int B  = in_sizes[3] / NBg;     // 16
  size_t nBA = (size_t)B * NA;

  float* out_tb = (float*)d_out;              // (B,NA,4)
  float* out_ts = out_tb + nBA * 4;           // (B,NA,80)
  float* out_fg = out_ts + nBA * NCg;         // (B,NA)

  char* ws = (char*)d_ws;
  size_t off = 0;
  float* align = (float*)(ws + off);          off += nBA * NBg * 4;   // 34.4 MB
  unsigned char* maskT = (unsigned char*)(ws + off); off += nBA * NBg; // 8.6 MB
  int* tgt = (int*)(ws + off);                off += nBA * 4;
  float* posAlign = (float*)(ws + off);       off += (size_t)B * NBg * 4;
  float* posOv = (float*)(ws + off);          off += (size_t)B * NBg * 4;

  hipMemsetAsync(maskT, 0, nBA * NBg, stream);
  hipMemsetAsync(posAlign, 0, (size_t)B * NBg * 4 * 2, stream);

  dim3 blk(256);
  dim3 gA((NA + 255) / 256, B);
  k1_align<<<gA, blk, 0, stream>>>(pd_scores, pd_bboxes, anc, gt_labels, gt_bboxes,
                                   mask_gt, align, NA);
  int rows = B * NBg;                  // 1024 rows, 4 waves/block
  k2_topk<<<rows / 4, blk, 0, stream>>>(align, anc, gt_bboxes, mask_gt, maskT, NA);
  k3_resolve<<<gA, blk, 0, stream>>>(pd_bboxes, anc, gt_bboxes, mask_gt, maskT, align,
                                     tgt, out_tb, out_fg, posAlign, posOv, NA);
  k5_scores<<<gA, blk, 0, stream>>>(gt_labels, tgt, out_fg, align, posAlign, posOv,
                                    out_ts, NA);
}

// Round 4
// 205.064 us; speedup vs baseline: 2.0592x; 1.3718x over previous
//
#include <hip/hip_runtime.h>
#include <cstdint>
#include <cstddef>

#define NBg 64    // num gt slots
#define NCg 80    // num classes
#define KTOP 10

// CIoU exactly mirroring the reference op order, f32, no FMA contraction.
// atan done in double then rounded -> approximates correctly-rounded f32 libm.
__device__ __forceinline__ float ciou_dev(float gx1, float gy1, float gx2, float gy2,
                                          float px1, float py1, float px2, float py2) {
#pragma clang fp contract(off)
  const float keps = 1e-7f;
  float w1 = gx2 - gx1;
  float h1 = (gy2 - gy1) + keps;
  float w2 = px2 - px1;
  float h2 = (py2 - py1) + keps;
  float iw = fminf(gx2, px2) - fmaxf(gx1, px1);
  float ih = fminf(gy2, py2) - fmaxf(gy1, py1);
  float inter = fmaxf(iw, 0.0f) * fmaxf(ih, 0.0f);
  float uni = w1 * h1 + w2 * h2 - inter + keps;
  float iou = inter / uni;
  float cw = fmaxf(gx2, px2) - fminf(gx1, px1);
  float ch = fmaxf(gy2, py2) - fminf(gy1, py1);
  float c2 = cw * cw + ch * ch + keps;
  float dx = (gx1 + gx2) * 0.5f - (px1 + px2) * 0.5f;
  float dy = (gy1 + gy2) * 0.5f - (py1 + py2) * 0.5f;
  float rho2 = dx * dx + dy * dy;
  float q2 = w2 / h2;
  float q1 = w1 / h1;
  float t = (float)atan((double)q2) - (float)atan((double)q1);
  float v = 0.4052847345693511f * (t * t);
  float alpha = v / ((v - iou) + 1.0000001f);
  return iou - (rho2 / c2 + v * alpha);
}

// K1: align_metric[b][j][a] for valid j; also zeroes maskT rows (kills a memset).
__global__ void k1_align(const float* __restrict__ pd_scores,
                         const float* __restrict__ pd_bboxes,
                         const float* __restrict__ anc,
                         const float* __restrict__ gt_labels,
                         const float* __restrict__ gt_bboxes,
                         const int* __restrict__ mask_gt,
                         float* __restrict__ align,
                         unsigned char* __restrict__ maskT,
                         int NA) {
  int b = blockIdx.y;
  int a = blockIdx.x * blockDim.x + threadIdx.x;
  __shared__ float4 sg[NBg];
  __shared__ int slbl[NBg];
  __shared__ int svalid[NBg];
  __shared__ int sglpos[NBg];
  if (threadIdx.x < NBg) {
    int j = threadIdx.x;
    const float* g = gt_bboxes + ((size_t)b * NBg + j) * 4;
    sg[j] = make_float4(g[0], g[1], g[2], g[3]);
    float gl = gt_labels[b * NBg + j];
    slbl[j] = gl > 0.0f ? (int)gl : 0;
    sglpos[j] = (gl >= 0.0f) ? 1 : 0;
    svalid[j] = mask_gt[b * NBg + j];
  }
  __syncthreads();
  if (a >= NA) return;
  // zero this anchor's maskT row (64 bytes)
  uint4* mrow = (uint4*)(maskT + ((size_t)b * NA + a) * NBg);
  uint4 z = {0u, 0u, 0u, 0u};
  mrow[0] = z; mrow[1] = z; mrow[2] = z; mrow[3] = z;

  float ax = anc[2 * a], ay = anc[2 * a + 1];
  const float* pb = pd_bboxes + ((size_t)b * NA + a) * 4;
  float px1 = pb[0], py1 = pb[1], px2 = pb[2], py2 = pb[3];
  const float* ps = pd_scores + ((size_t)b * NA + a) * NCg;
  for (int j = 0; j < NBg; j++) {
    if (!svalid[j]) continue;
    float4 g = sg[j];
    float dmin = fminf(fminf(ax - g.x, ay - g.y), fminf(g.z - ax, g.w - ay));
    float am = 0.0f;
    if (dmin > 1e-9f) {
      float ci = ciou_dev(g.x, g.y, g.z, g.w, px1, py1, px2, py2);
      float ov = ci > 0.0f ? ci : 0.0f;
      float sc = sglpos[j] ? ps[slbl[j]] : 0.0f;
      // power(sc,0.5) == CR sqrt; power(ov,6) via double products.
      float f1 = (float)sqrt((double)sc);
      double o = (double)ov;
      double o3 = o * o * o;
      float f2 = (float)(o3 * o3);
      am = f1 * f2;
    }
    align[((size_t)(b * NBg + j)) * NA + a] = am;
  }
}

// K2: exact top-10 per (b,j) row, jax tie semantics (value desc, index asc).
// One block (4 waves) per row. Batched float4 loads -> per-lane sorted top-10
// -> per-wave butterfly pop-merge -> 40-candidate final merge on wave 0.
// Also zero-inits posAlign/posOv (kills a memset).
__global__ void k2_topk(const float* __restrict__ align,
                        const float* __restrict__ anc,
                        const float* __restrict__ gt_bboxes,
                        const int* __restrict__ mask_gt,
                        unsigned char* __restrict__ maskT,
                        float* __restrict__ posAlign,
                        float* __restrict__ posOv,
                        int NA) {
  int row = blockIdx.x;            // b*64 + j
  int tid = threadIdx.x;
  int lane = tid & 63;
  int wid = tid >> 6;
  if (tid == 0) { posAlign[row] = 0.0f; posOv[row] = 0.0f; }
  int b = row >> 6;
  int j = row & 63;
  if (!mask_gt[row]) return;       // block-uniform
  const float4* r4 = (const float4*)(align + (size_t)row * NA);
  int na4 = NA >> 2;               // 2100

  float4 q[9];
#pragma unroll
  for (int it = 0; it < 9; it++) {
    int idx = tid + (it << 8);
    if (idx < na4) q[it] = r4[idx];
  }

  float v[KTOP];
  int id[KTOP];
#pragma unroll
  for (int k = 0; k < KTOP; k++) { v[k] = -1.0f; id[k] = 1 << 30; }

  auto ins = [&](float val, int a) {
    if (val > v[KTOP - 1] || (val == v[KTOP - 1] && a < id[KTOP - 1])) {
      v[KTOP - 1] = val; id[KTOP - 1] = a;
#pragma unroll
      for (int k = KTOP - 1; k > 0; k--) {
        bool sw = v[k] > v[k - 1] || (v[k] == v[k - 1] && id[k] < id[k - 1]);
        if (sw) {
          float tv = v[k]; v[k] = v[k - 1]; v[k - 1] = tv;
          int ti = id[k]; id[k] = id[k - 1]; id[k - 1] = ti;
        }
      }
    }
  };

#pragma unroll
  for (int it = 0; it < 9; it++) {
    int idx = tid + (it << 8);
    if (idx < na4) {
      int base = idx << 2;
      ins(q[it].x, base);
      ins(q[it].y, base + 1);
      ins(q[it].z, base + 2);
      ins(q[it].w, base + 3);
    }
  }

  // per-wave pop-merge: 10 rounds, winner of round p held by lane p
  float myval = 0.0f; int mysel = 0;
#pragma unroll
  for (int p = 0; p < KTOP; p++) {
    float bv = v[0]; int bi = id[0];
#pragma unroll
    for (int m = 1; m < 64; m <<= 1) {
      float ov_ = __shfl_xor(bv, m, 64);
      int oi = __shfl_xor(bi, m, 64);
      if (ov_ > bv || (ov_ == bv && oi < bi)) { bv = ov_; bi = oi; }
    }
    if (lane == p) { myval = bv; mysel = bi; }
    if (id[0] == bi) {   // this lane owned the winner: pop it
#pragma unroll
      for (int k = 0; k < KTOP - 1; k++) { v[k] = v[k + 1]; id[k] = id[k + 1]; }
      v[KTOP - 1] = -1.0f; id[KTOP - 1] = 1 << 30;
    }
  }

  __shared__ float lv[4 * KTOP];
  __shared__ int li[4 * KTOP];
  if (lane < KTOP) { lv[wid * KTOP + lane] = myval; li[wid * KTOP + lane] = mysel; }
  __syncthreads();
  if (wid != 0) return;

  // final merge of 40 unique-index candidates across wave 0's lanes
  float cv = (lane < 4 * KTOP) ? lv[lane] : -1.0f;
  int ci = (lane < 4 * KTOP) ? li[lane] : (1 << 30);
  int sel = 0;
#pragma unroll
  for (int p = 0; p < KTOP; p++) {
    float bv = cv; int bi = ci;
#pragma unroll
    for (int m = 1; m < 64; m <<= 1) {
      float ov_ = __shfl_xor(bv, m, 64);
      int oi = __shfl_xor(bi, m, 64);
      if (ov_ > bv || (ov_ == bv && oi < bi)) { bv = ov_; bi = oi; }
    }
    if (lane == p) sel = bi;
    if (ci == bi) { cv = -1.0f; ci = 1 << 30; }  // indices unique -> exact pop
  }

  if (lane < KTOP) {
    int a = sel;
    float ax = anc[2 * a], ay = anc[2 * a + 1];
    const float* g = gt_bboxes + ((size_t)b * NBg + j) * 4;
    float dmin = fminf(fminf(ax - g[0], ay - g[1]), fminf(g[2] - ax, g[3] - ay));
    if (dmin > 1e-9f) maskT[((size_t)b * NA + a) * NBg + j] = 1;
  }
}

// K3: per (b,a) resolve multi-matches, write target_bboxes + fg, target idx,
// and atomic-max pos_align / pos_overlaps per gt.
__global__ void k3_resolve(const float* __restrict__ pd_bboxes,
                           const float* __restrict__ anc,
                           const float* __restrict__ gt_bboxes,
                           const int* __restrict__ mask_gt,
                           const unsigned char* __restrict__ maskT,
                           const float* __restrict__ align,
                           int* __restrict__ tgt,
                           float* __restrict__ out_tb,
                           float* __restrict__ out_fg,
                           float* __restrict__ posAlign,
                           float* __restrict__ posOv,
                           int NA) {
  int b = blockIdx.y;
  int a = blockIdx.x * blockDim.x + threadIdx.x;
  __shared__ float4 sg[NBg];
  __shared__ int svalid[NBg];
  if (threadIdx.x < NBg) {
    int j = threadIdx.x;
    const float* g = gt_bboxes + ((size_t)b * NBg + j) * 4;
    sg[j] = make_float4(g[0], g[1], g[2], g[3]);
    svalid[j] = mask_gt[b * NBg + j];
  }
  __syncthreads();
  if (a >= NA) return;
  const unsigned int* mu = (const unsigned int*)(maskT + ((size_t)b * NA + a) * NBg);
  int cnt = 0, first = 0;
  bool any = false;
  for (int w = 0; w < 16; w++) {
    unsigned int x = mu[w];
    if (x) {
      cnt += __popc(x);
      if (!any) { first = w * 4 + ((__ffs(x) - 1) >> 3); any = true; }
    }
  }
  float ax = anc[2 * a], ay = anc[2 * a + 1];
  const float* pb = pd_bboxes + ((size_t)b * NA + a) * 4;
  float px1 = pb[0], py1 = pb[1], px2 = pb[2], py2 = pb[3];
  int t = 0;
  float fg = 0.0f;
  float ovt = -1.0f;
  if (cnt == 1) {
    t = first; fg = 1.0f;
  } else if (cnt > 1) {
    float best = -1.0f;
    for (int jj = 0; jj < NBg; jj++) {
      float ov = 0.0f;
      if (svalid[jj]) {
        float4 g = sg[jj];
        float dmin = fminf(fminf(ax - g.x, ay - g.y), fminf(g.z - ax, g.w - ay));
        if (dmin > 1e-9f) {
          float ci = ciou_dev(g.x, g.y, g.z, g.w, px1, py1, px2, py2);
          ov = ci > 0.0f ? ci : 0.0f;
        }
      }
      if (ov > best) { best = ov; t = jj; }
    }
    fg = 1.0f;
    ovt = best;
  }
  tgt[(size_t)b * NA + a] = t;
  out_fg[(size_t)b * NA + a] = fg;
  float4 gb = sg[t];
  ((float4*)out_tb)[(size_t)b * NA + a] = gb;
  if (fg > 0.0f) {
    float av = align[((size_t)(b * NBg + t)) * NA + a];
    atomicMax((int*)(posAlign + b * NBg + t), __float_as_int(av));
    float ov;
    if (ovt >= 0.0f) {
      ov = ovt;
    } else {
      float4 g = sg[t];
      float ci = ciou_dev(g.x, g.y, g.z, g.w, px1, py1, px2, py2);
      ov = ci > 0.0f ? ci : 0.0f;
    }
    atomicMax((int*)(posOv + b * NBg + t), __float_as_int(ov));
  }
}

// K5: norm + one-hot target_scores, coalesced block-wide writes.
__global__ void k5_scores(const float* __restrict__ gt_labels,
                          const int* __restrict__ tgt,
                          const float* __restrict__ out_fg,
                          const float* __restrict__ align,
                          const float* __restrict__ posAlign,
                          const float* __restrict__ posOv,
                          float* __restrict__ out_ts,
                          int NA) {
  int b = blockIdx.y;
  int a0 = blockIdx.x * 256;
  int tid = threadIdx.x;
  int a = a0 + tid;
  __shared__ float snorm[256];
  __shared__ int slab[256];
  float norm = 0.0f;
  int lbl = -1;
  if (a < NA) {
    int t = tgt[(size_t)b * NA + a];
    float fg = out_fg[(size_t)b * NA + a];
    if (fg > 0.0f) {
      float av = align[((size_t)(b * NBg + t)) * NA + a];
      norm = av * posOv[b * NBg + t] / (posAlign[b * NBg + t] + 1e-9f);
      float gl = gt_labels[b * NBg + t];
      lbl = gl > 0.0f ? (int)gl : 0;
    }
  }
  snorm[tid] = norm;
  slab[tid] = lbl;
  __syncthreads();
  int nanch = NA - a0; if (nanch > 256) nanch = 256;
  int nf4 = nanch * (NCg / 4);     // float4s to write for this block
  float4* o = (float4*)(out_ts + ((size_t)b * NA + a0) * NCg);
  for (int i = tid; i < nf4; i += 256) {
    int aa = i / (NCg / 4);
    int c0 = (i % (NCg / 4)) * 4;
    int lb = slab[aa];
    float nv = snorm[aa];
    float4 w = make_float4(0.0f, 0.0f, 0.0f, 0.0f);
    int d = lb - c0;
    if (d >= 0 && d < 4) ((float*)&w)[d] = nv;
    o[i] = w;
  }
}

extern "C" void kernel_launch(void* const* d_in, const int* in_sizes, int n_in,
                              void* d_out, int out_size, void* d_ws, size_t ws_size,
                              hipStream_t stream) {
  const float* pd_scores = (const float*)d_in[0];
  const float* pd_bboxes = (const float*)d_in[1];
  const float* anc       = (const float*)d_in[2];
  const float* gt_labels = (const float*)d_in[3];
  const float* gt_bboxes = (const float*)d_in[4];
  const int*   mask_gt   = (const int*)d_in[5];

  int NA = in_sizes[2] / 2;       // 8400
  int B  = in_sizes[3] / NBg;     // 16
  size_t nBA = (size_t)B * NA;

  float* out_tb = (float*)d_out;              // (B,NA,4)
  float* out_ts = out_tb + nBA * 4;           // (B,NA,80)
  float* out_fg = out_ts + nBA * NCg;         // (B,NA)

  char* ws = (char*)d_ws;
  size_t off = 0;
  float* align = (float*)(ws + off);          off += nBA * NBg * 4;   // 34.4 MB
  unsigned char* maskT = (unsigned char*)(ws + off); off += nBA * NBg; // 8.6 MB
  int* tgt = (int*)(ws + off);                off += nBA * 4;
  float* posAlign = (float*)(ws + off);       off += (size_t)B * NBg * 4;
  float* posOv = (float*)(ws + off);          off += (size_t)B * NBg * 4;

  dim3 blk(256);
  dim3 gA((NA + 255) / 256, B);
  k1_align<<<gA, blk, 0, stream>>>(pd_scores, pd_bboxes, anc, gt_labels, gt_bboxes,
                                   mask_gt, align, maskT, NA);
  int rows = B * NBg;                  // 1024 rows, 1 block each
  k2_topk<<<rows, blk, 0, stream>>>(align, anc, gt_bboxes, mask_gt, maskT,
                                    posAlign, posOv, NA);
  k3_resolve<<<gA, blk, 0, stream>>>(pd_bboxes, anc, gt_bboxes, mask_gt, maskT, align,
                                     tgt, out_tb, out_fg, posAlign, posOv, NA);
  k5_scores<<<gA, blk, 0, stream>>>(gt_labels, tgt, out_fg, align, posAlign, posOv,
                                    out_ts, NA);
}

// Round 5
// 180.016 us; speedup vs baseline: 2.3458x; 1.1391x over previous
//
#include <hip/hip_runtime.h>
#include <cstdint>
#include <cstddef>

#define NBg 64    // num gt slots
#define NCg 80    // num classes
#define KTOP 10

// CIoU exactly mirroring the reference op order, f32, no FMA contraction.
// atan done in double then rounded -> approximates correctly-rounded f32 libm.
__device__ __forceinline__ float ciou_dev(float gx1, float gy1, float gx2, float gy2,
                                          float px1, float py1, float px2, float py2) {
#pragma clang fp contract(off)
  const float keps = 1e-7f;
  float w1 = gx2 - gx1;
  float h1 = (gy2 - gy1) + keps;
  float w2 = px2 - px1;
  float h2 = (py2 - py1) + keps;
  float iw = fminf(gx2, px2) - fmaxf(gx1, px1);
  float ih = fminf(gy2, py2) - fmaxf(gy1, py1);
  float inter = fmaxf(iw, 0.0f) * fmaxf(ih, 0.0f);
  float uni = w1 * h1 + w2 * h2 - inter + keps;
  float iou = inter / uni;
  float cw = fmaxf(gx2, px2) - fminf(gx1, px1);
  float ch = fmaxf(gy2, py2) - fminf(gy1, py1);
  float c2 = cw * cw + ch * ch + keps;
  float dx = (gx1 + gx2) * 0.5f - (px1 + px2) * 0.5f;
  float dy = (gy1 + gy2) * 0.5f - (py1 + py2) * 0.5f;
  float rho2 = dx * dx + dy * dy;
  float q2 = w2 / h2;
  float q1 = w1 / h1;
  float t = (float)atan((double)q2) - (float)atan((double)q1);
  float v = 0.4052847345693511f * (t * t);
  float alpha = v / ((v - iou) + 1.0000001f);
  return iou - (rho2 / c2 + v * alpha);
}

// am = sqrt(score) * overlap^6 with the exact double-rounded forms used since r1.
__device__ __forceinline__ float am_dev(float sc, float ov) {
  float f1 = (float)sqrt((double)sc);
  double o = (double)ov;
  double o3 = o * o * o;
  return f1 * (float)(o3 * o3);
}

// KA: fused metric + exact top-10 per (b,j) row (jax tie semantics: value desc,
// index asc). One block (4 waves) per row. Metrics computed on the fly (CIoU
// only for in-box anchors). Emits sel[row][10] = anchor index or -1 (filtered
// by in-gts / invalid row). Also zero-inits posAlign/posOv.
__global__ void ka_topk(const float* __restrict__ pd_scores,
                        const float* __restrict__ pd_bboxes,
                        const float* __restrict__ anc,
                        const float* __restrict__ gt_labels,
                        const float* __restrict__ gt_bboxes,
                        const int* __restrict__ mask_gt,
                        int* __restrict__ sel,
                        float* __restrict__ posAlign,
                        float* __restrict__ posOv,
                        int NA) {
  int row = blockIdx.x;            // b*64 + j
  int tid = threadIdx.x;
  int lane = tid & 63;
  int wid = tid >> 6;
  if (tid == 0) { posAlign[row] = 0.0f; posOv[row] = 0.0f; }
  if (!mask_gt[row]) {             // block-uniform
    if (tid < KTOP) sel[row * KTOP + tid] = -1;
    return;
  }
  int b = row >> 6;
  const float* g = gt_bboxes + (size_t)row * 4;
  float gx1 = g[0], gy1 = g[1], gx2 = g[2], gy2 = g[3];
  float gl = gt_labels[row];
  int lbl = gl > 0.0f ? (int)gl : 0;
  bool glpos = (gl >= 0.0f);
  const float2* anc2 = (const float2*)anc;

  float v[KTOP];
  int id[KTOP];
#pragma unroll
  for (int k = 0; k < KTOP; k++) { v[k] = -1.0f; id[k] = 1 << 30; }

  auto ins = [&](float val, int a) {
    if (val > v[KTOP - 1] || (val == v[KTOP - 1] && a < id[KTOP - 1])) {
      v[KTOP - 1] = val; id[KTOP - 1] = a;
#pragma unroll
      for (int k = KTOP - 1; k > 0; k--) {
        bool sw = v[k] > v[k - 1] || (v[k] == v[k - 1] && id[k] < id[k - 1]);
        if (sw) {
          float tv = v[k]; v[k] = v[k - 1]; v[k - 1] = tv;
          int ti = id[k]; id[k] = id[k - 1]; id[k - 1] = ti;
        }
      }
    }
  };

  for (int a = tid; a < NA; a += 256) {     // ascending per-lane index order
    float2 ap = anc2[a];
    float dmin = fminf(fminf(ap.x - gx1, ap.y - gy1),
                       fminf(gx2 - ap.x, gy2 - ap.y));
    float am = 0.0f;
    if (dmin > 1e-9f) {
      const float* pb = pd_bboxes + ((size_t)b * NA + a) * 4;
      float ci = ciou_dev(gx1, gy1, gx2, gy2, pb[0], pb[1], pb[2], pb[3]);
      float ov = ci > 0.0f ? ci : 0.0f;
      float sc = glpos ? pd_scores[((size_t)b * NA + a) * NCg + lbl] : 0.0f;
      am = am_dev(sc, ov);
    }
    ins(am, a);
  }

  // per-wave pop-merge: 10 rounds, winner of round p held by lane p
  float myval = 0.0f; int mysel = 0;
#pragma unroll
  for (int p = 0; p < KTOP; p++) {
    float bv = v[0]; int bi = id[0];
#pragma unroll
    for (int m = 1; m < 64; m <<= 1) {
      float ov_ = __shfl_xor(bv, m, 64);
      int oi = __shfl_xor(bi, m, 64);
      if (ov_ > bv || (ov_ == bv && oi < bi)) { bv = ov_; bi = oi; }
    }
    if (lane == p) { myval = bv; mysel = bi; }
    if (id[0] == bi) {   // this lane owned the winner: pop it
#pragma unroll
      for (int k = 0; k < KTOP - 1; k++) { v[k] = v[k + 1]; id[k] = id[k + 1]; }
      v[KTOP - 1] = -1.0f; id[KTOP - 1] = 1 << 30;
    }
  }

  __shared__ float lv[4 * KTOP];
  __shared__ int li[4 * KTOP];
  if (lane < KTOP) { lv[wid * KTOP + lane] = myval; li[wid * KTOP + lane] = mysel; }
  __syncthreads();
  if (wid != 0) return;

  // final merge of 40 unique-index candidates across wave 0's lanes
  float cv = (lane < 4 * KTOP) ? lv[lane] : -1.0f;
  int ci = (lane < 4 * KTOP) ? li[lane] : (1 << 30);
  int selw = 0;
#pragma unroll
  for (int p = 0; p < KTOP; p++) {
    float bv = cv; int bi = ci;
#pragma unroll
    for (int m = 1; m < 64; m <<= 1) {
      float ov_ = __shfl_xor(bv, m, 64);
      int oi = __shfl_xor(bi, m, 64);
      if (ov_ > bv || (ov_ == bv && oi < bi)) { bv = ov_; bi = oi; }
    }
    if (lane == p) selw = bi;
    if (ci == bi) { cv = -1.0f; ci = 1 << 30; }  // indices unique -> exact pop
  }

  if (lane < KTOP) {
    int a = selw;
    float2 ap = anc2[a];
    float dmin = fminf(fminf(ap.x - gx1, ap.y - gy1),
                       fminf(gx2 - ap.x, gy2 - ap.y));
    sel[row * KTOP + lane] = (dmin > 1e-9f) ? a : -1;  // in-gts filter
  }
}

// K3: per (b,a): build 64-bit gt-match mask from sel lists via LDS scatter,
// resolve multi-matches by first-argmax of overlaps, write target bbox/fg/idx,
// recompute am (bit-identical) and atomic-max posAlign/posOv; stash amv.
__global__ void k3_resolve(const float* __restrict__ pd_scores,
                           const float* __restrict__ pd_bboxes,
                           const float* __restrict__ anc,
                           const float* __restrict__ gt_labels,
                           const float* __restrict__ gt_bboxes,
                           const int* __restrict__ mask_gt,
                           const int* __restrict__ sel,
                           int* __restrict__ tgt,
                           float* __restrict__ amv,
                           float* __restrict__ out_tb,
                           float* __restrict__ out_fg,
                           float* __restrict__ posAlign,
                           float* __restrict__ posOv,
                           int NA) {
  int b = blockIdx.y;
  int tid = threadIdx.x;
  int a0 = blockIdx.x * 256;
  int a = a0 + tid;
  __shared__ float4 sg[NBg];
  __shared__ int svalid[NBg];
  __shared__ int slbl[NBg];
  __shared__ int sglpos[NBg];
  __shared__ unsigned int mlo[256];
  __shared__ unsigned int mhi[256];
  mlo[tid] = 0u; mhi[tid] = 0u;
  if (tid < NBg) {
    int j = tid;
    const float* g = gt_bboxes + ((size_t)b * NBg + j) * 4;
    sg[j] = make_float4(g[0], g[1], g[2], g[3]);
    svalid[j] = mask_gt[b * NBg + j];
    float gl = gt_labels[b * NBg + j];
    slbl[j] = gl > 0.0f ? (int)gl : 0;
    sglpos[j] = (gl >= 0.0f) ? 1 : 0;
  }
  __syncthreads();
  // scatter sel entries of this batch into per-anchor bitmasks
  for (int i = tid; i < NBg * KTOP; i += 256) {
    int e = sel[b * NBg * KTOP + i];
    int d = e - a0;
    if (d >= 0 && d < 256) {
      int j = i / KTOP;
      unsigned int bit = 1u << (j & 31);
      if (j < 32) atomicOr(&mlo[d], bit); else atomicOr(&mhi[d], bit);
    }
  }
  __syncthreads();
  if (a >= NA) return;
  unsigned int lo = mlo[tid], hi = mhi[tid];
  int cnt = __popc(lo) + __popc(hi);
  int first = lo ? (__ffs(lo) - 1) : (hi ? 32 + __ffs(hi) - 1 : 0);

  float ax = anc[2 * a], ay = anc[2 * a + 1];
  float px1 = 0.f, py1 = 0.f, px2 = 0.f, py2 = 0.f;
  if (cnt > 0) {
    const float* pb = pd_bboxes + ((size_t)b * NA + a) * 4;
    px1 = pb[0]; py1 = pb[1]; px2 = pb[2]; py2 = pb[3];
  }
  int t = 0;
  float fg = 0.0f;
  float ovt = -1.0f;
  if (cnt == 1) {
    t = first; fg = 1.0f;
  } else if (cnt > 1) {
    // first-argmax_j overlaps[b,j,a] (jnp.argmax semantics)
    float best = -1.0f;
    for (int jj = 0; jj < NBg; jj++) {
      float ov = 0.0f;
      if (svalid[jj]) {
        float4 g = sg[jj];
        float dmin = fminf(fminf(ax - g.x, ay - g.y), fminf(g.z - ax, g.w - ay));
        if (dmin > 1e-9f) {
          float ci = ciou_dev(g.x, g.y, g.z, g.w, px1, py1, px2, py2);
          ov = ci > 0.0f ? ci : 0.0f;
        }
      }
      if (ov > best) { best = ov; t = jj; }
    }
    fg = 1.0f;
    ovt = best;
  }
  tgt[(size_t)b * NA + a] = t;
  out_fg[(size_t)b * NA + a] = fg;
  float4 gb = sg[t];
  ((float4*)out_tb)[(size_t)b * NA + a] = gb;
  float amval = 0.0f;
  if (fg > 0.0f) {
    float ov;
    if (ovt >= 0.0f) {
      ov = ovt;
    } else {
      float ci = ciou_dev(gb.x, gb.y, gb.z, gb.w, px1, py1, px2, py2);
      ov = ci > 0.0f ? ci : 0.0f;   // t came from sel -> in-box & valid
    }
    float sc = sglpos[t] ? pd_scores[((size_t)b * NA + a) * NCg + slbl[t]] : 0.0f;
    amval = am_dev(sc, ov);
    atomicMax((int*)(posAlign + b * NBg + t), __float_as_int(amval));
    atomicMax((int*)(posOv + b * NBg + t), __float_as_int(ov));
  }
  amv[(size_t)b * NA + a] = amval;
}

// K5: norm + one-hot target_scores, coalesced block-wide writes.
__global__ void k5_scores(const float* __restrict__ gt_labels,
                          const int* __restrict__ tgt,
                          const float* __restrict__ out_fg,
                          const float* __restrict__ amv,
                          const float* __restrict__ posAlign,
                          const float* __restrict__ posOv,
                          float* __restrict__ out_ts,
                          int NA) {
  int b = blockIdx.y;
  int a0 = blockIdx.x * 256;
  int tid = threadIdx.x;
  int a = a0 + tid;
  __shared__ float snorm[256];
  __shared__ int slab[256];
  float norm = 0.0f;
  int lbl = -1;
  if (a < NA) {
    int t = tgt[(size_t)b * NA + a];
    float fg = out_fg[(size_t)b * NA + a];
    if (fg > 0.0f) {
      float av = amv[(size_t)b * NA + a];
      norm = av * posOv[b * NBg + t] / (posAlign[b * NBg + t] + 1e-9f);
      float gl = gt_labels[b * NBg + t];
      lbl = gl > 0.0f ? (int)gl : 0;
    }
  }
  snorm[tid] = norm;
  slab[tid] = lbl;
  __syncthreads();
  int nanch = NA - a0; if (nanch > 256) nanch = 256;
  int nf4 = nanch * (NCg / 4);     // float4s to write for this block
  float4* o = (float4*)(out_ts + ((size_t)b * NA + a0) * NCg);
  for (int i = tid; i < nf4; i += 256) {
    int aa = i / (NCg / 4);
    int c0 = (i % (NCg / 4)) * 4;
    int lb = slab[aa];
    float nv = snorm[aa];
    float4 w = make_float4(0.0f, 0.0f, 0.0f, 0.0f);
    int d = lb - c0;
    if (d >= 0 && d < 4) ((float*)&w)[d] = nv;
    o[i] = w;
  }
}

extern "C" void kernel_launch(void* const* d_in, const int* in_sizes, int n_in,
                              void* d_out, int out_size, void* d_ws, size_t ws_size,
                              hipStream_t stream) {
  const float* pd_scores = (const float*)d_in[0];
  const float* pd_bboxes = (const float*)d_in[1];
  const float* anc       = (const float*)d_in[2];
  const float* gt_labels = (const float*)d_in[3];
  const float* gt_bboxes = (const float*)d_in[4];
  const int*   mask_gt   = (const int*)d_in[5];

  int NA = in_sizes[2] / 2;       // 8400
  int B  = in_sizes[3] / NBg;     // 16
  size_t nBA = (size_t)B * NA;

  float* out_tb = (float*)d_out;              // (B,NA,4)
  float* out_ts = out_tb + nBA * 4;           // (B,NA,80)
  float* out_fg = out_ts + nBA * NCg;         // (B,NA)

  char* ws = (char*)d_ws;
  size_t off = 0;
  int* sel = (int*)(ws + off);                off += (size_t)B * NBg * KTOP * 4;
  int* tgt = (int*)(ws + off);                off += nBA * 4;
  float* amv = (float*)(ws + off);            off += nBA * 4;
  float* posAlign = (float*)(ws + off);       off += (size_t)B * NBg * 4;
  float* posOv = (float*)(ws + off);          off += (size_t)B * NBg * 4;

  dim3 blk(256);
  int rows = B * NBg;                  // 1024 rows, 1 block each
  ka_topk<<<rows, blk, 0, stream>>>(pd_scores, pd_bboxes, anc, gt_labels,
                                    gt_bboxes, mask_gt, sel, posAlign, posOv, NA);
  dim3 gA((NA + 255) / 256, B);
  k3_resolve<<<gA, blk, 0, stream>>>(pd_scores, pd_bboxes, anc, gt_labels,
                                     gt_bboxes, mask_gt, sel, tgt, amv,
                                     out_tb, out_fg, posAlign, posOv, NA);
  k5_scores<<<gA, blk, 0, stream>>>(gt_labels, tgt, out_fg, amv, posAlign, posOv,
                                    out_ts, NA);
}